// Round 6
// baseline (685.744 us; speedup 1.0000x reference)
//
#include <hip/hip_runtime.h>

typedef float f32x2 __attribute__((ext_vector_type(2)));
typedef float f32x4 __attribute__((ext_vector_type(4)));

#define BB 256
#define TT 1024
#define HH 128
#define CC 2

// tanh(u) = 1 - 2/(exp(2u)+1); branchless. Validated R3/R4: absmax 9.77e-4.
__device__ __forceinline__ float ftanh(float u) {
    float e = __expf(2.0f * u);
    float r = __builtin_amdgcn_rcpf(e + 1.0f);
    return fmaf(-2.0f, r, 1.0f);
}

// broadcast lane j's value to all lanes via SGPR (VALU pipe, not LDS pipe)
__device__ __forceinline__ float bcast(float v, int j) {
    return __int_as_float(__builtin_amdgcn_readlane(__float_as_int(v), j));
}

__global__ __launch_bounds__(128, 1) void rnn_kernel(
    const float* __restrict__ x, const float* __restrict__ W_ih,
    const float* __restrict__ W_hh, const float* __restrict__ b_ih,
    const float* __restrict__ b_hh, const float* __restrict__ W_fc,
    const float* __restrict__ b_fc, float* __restrict__ out)
{
    const int b   = blockIdx.x;
    const int tid = threadIdx.x;        // 0..127
    const int l   = tid & 63;
    const int wv  = tid >> 6;           // 0..1
    const int krow  = wv << 6;          // this wave's K-range base
    const int rkeep = krow + l;         // row finalized here == own h index
    const int rship = (64 - krow) + l;  // row whose partial is shipped across

    __shared__ float xs[TT];            // input sequence
    __shared__ float pship[2][2][64];   // [buf][src wave][lane] partial dots
    __shared__ f32x2 qp[2][2];          // [buf][wave] logit partials

    // preload x row (coalesced f32x4)
    {
        const f32x4* xr = (const f32x4*)(x + (size_t)b * TT);
        f32x4* xd = (f32x4*)xs;
        xd[tid]       = xr[tid];
        xd[tid + 128] = xr[tid + 128];
    }

    const float wih  = W_ih[rkeep];               // INPUT_DIM = 1
    const float bias = b_ih[rkeep] + b_hh[rkeep];
    const float wf0  = W_fc[rkeep];               // class-0 weight for own h idx
    const float wf1  = W_fc[HH + rkeep];          // class-1
    const float bf0  = b_fc[0], bf1 = b_fc[1];

    // weights for the two rows this lane computes, over its wave's K-half:
    // wk = W_hh[rkeep][krow..krow+63], ws = W_hh[rship][krow..krow+63]
    // 128 fp32 = 128 VGPRs (fits; R4 proved no spill at this size)
    f32x4 wk[16], ws[16];
    {
        const f32x4* pk_ = (const f32x4*)(W_hh + (size_t)rkeep * HH + krow);
        const f32x4* ps_ = (const f32x4*)(W_hh + (size_t)rship * HH + krow);
        #pragma unroll
        for (int j = 0; j < 16; ++j) { wk[j] = pk_[j]; ws[j] = ps_[j]; }
    }

    float hn = 0.f;                     // own h element: h[rkeep] = h[krow+l]
    float* o = out + (size_t)b * TT * CC;

    __syncthreads();                    // xs visible

    // step t: entry hn = h_t[rkeep]. Computes logits(h_t) -> out[t-1],
    // and h_{t+1}. One barrier, 2 tiny LDS roundtrips, zero h broadcast on LDS.
    #pragma unroll 2
    for (int t = 0; t < TT; ++t) {
        const int buf = t & 1;

        // ---- partial dots over k in [krow, krow+64): h via readlane (VALU)
        float ak0=0.f, ak1=0.f, ak2=0.f, ak3=0.f;
        float as0=0.f, as1=0.f, as2=0.f, as3=0.f;
        #pragma unroll
        for (int j = 0; j < 16; ++j) {
            float s0 = bcast(hn, 4*j+0);
            float s1 = bcast(hn, 4*j+1);
            float s2 = bcast(hn, 4*j+2);
            float s3 = bcast(hn, 4*j+3);
            ak0 = fmaf(wk[j].x, s0, ak0);  as0 = fmaf(ws[j].x, s0, as0);
            ak1 = fmaf(wk[j].y, s1, ak1);  as1 = fmaf(ws[j].y, s1, as1);
            ak2 = fmaf(wk[j].z, s2, ak2);  as2 = fmaf(ws[j].z, s2, as2);
            ak3 = fmaf(wk[j].w, s3, ak3);  as3 = fmaf(ws[j].w, s3, as3);
        }
        float pk = (ak0 + ak1) + (ak2 + ak3);
        float ps = (as0 + as1) + (as2 + as3);
        pship[buf][wv][l] = ps;          // ship alien-row partial (1 b32 write)

        // ---- logit partials of h_t (off the recurrence chain; swizzles hide
        // under the fma stage's VALU issue — LDS pipe has slack now)
        float q0 = wf0 * hn, q1 = wf1 * hn;
        q0 += __shfl_xor(q0, 1);  q1 += __shfl_xor(q1, 1);
        q0 += __shfl_xor(q0, 2);  q1 += __shfl_xor(q1, 2);
        q0 += __shfl_xor(q0, 4);  q1 += __shfl_xor(q1, 4);
        q0 += __shfl_xor(q0, 8);  q1 += __shfl_xor(q1, 8);
        q0 += __shfl_xor(q0, 16); q1 += __shfl_xor(q1, 16);
        q0 += __shfl_xor(q0, 32); q1 += __shfl_xor(q1, 32);
        if (l == 0) { f32x2 qq = {q0, q1}; qp[buf][wv] = qq; }

        __syncthreads();                 // the single per-step barrier

        // ---- store out[t-1] = logits(h_t) (qp written pre-barrier)
        if (t > 0 && tid == 0) {
            f32x2 s = qp[buf][0] + qp[buf][1];
            s.x += bf0; s.y += bf1;
            *(f32x2*)(o + (t - 1) * CC) = s;
        }

        // ---- finalize own row: add cross-wave partial, bias, input; tanh
        float po = pship[buf][wv ^ 1][l];
        float u  = fmaf(xs[t], wih, bias) + (pk + po);
        hn = ftanh(u);
    }

    // epilogue: out[TT-1] = logits(h_TT)
    {
        float q0 = wf0 * hn, q1 = wf1 * hn;
        q0 += __shfl_xor(q0, 1);  q1 += __shfl_xor(q1, 1);
        q0 += __shfl_xor(q0, 2);  q1 += __shfl_xor(q1, 2);
        q0 += __shfl_xor(q0, 4);  q1 += __shfl_xor(q1, 4);
        q0 += __shfl_xor(q0, 8);  q1 += __shfl_xor(q1, 8);
        q0 += __shfl_xor(q0, 16); q1 += __shfl_xor(q1, 16);
        q0 += __shfl_xor(q0, 32); q1 += __shfl_xor(q1, 32);
        if (l == 0) { f32x2 qq = {q0, q1}; qp[0][wv] = qq; }
    }
    __syncthreads();
    if (tid == 0) {
        f32x2 s = qp[0][0] + qp[0][1];
        s.x += bf0; s.y += bf1;
        *(f32x2*)(o + (TT - 1) * CC) = s;
    }
}

extern "C" void kernel_launch(void* const* d_in, const int* in_sizes, int n_in,
                              void* d_out, int out_size, void* d_ws, size_t ws_size,
                              hipStream_t stream) {
    const float* x    = (const float*)d_in[0];
    const float* W_ih = (const float*)d_in[1];
    const float* W_hh = (const float*)d_in[2];
    const float* b_ih = (const float*)d_in[3];
    const float* b_hh = (const float*)d_in[4];
    const float* W_fc = (const float*)d_in[5];
    const float* b_fc = (const float*)d_in[6];
    float* out = (float*)d_out;

    rnn_kernel<<<BB, 128, 0, stream>>>(x, W_ih, W_hh, b_ih, b_hh, W_fc, b_fc, out);
}

// Round 7
// 625.318 us; speedup vs baseline: 1.0966x; 1.0966x over previous
//
#include <hip/hip_runtime.h>

typedef float f32x2 __attribute__((ext_vector_type(2)));
typedef float f32x4 __attribute__((ext_vector_type(4)));

#define BB 256
#define TT 1024
#define HH 128
#define CC 2

// tanh(u) = 1 - 2/(exp(2u)+1); branchless. Validated R3-R5: absmax 9.77e-4.
__device__ __forceinline__ float ftanh(float u) {
    float e = __expf(2.0f * u);
    float r = __builtin_amdgcn_rcpf(e + 1.0f);
    return fmaf(-2.0f, r, 1.0f);
}

// broadcast lane j's value to all lanes via SGPR (VALU pipe, not LDS pipe)
__device__ __forceinline__ float bcast(float v, int j) {
    return __int_as_float(__builtin_amdgcn_readlane(__float_as_int(v), j));
}

__global__ __launch_bounds__(256, 1) void rnn_kernel(
    const float* __restrict__ x, const float* __restrict__ W_ih,
    const float* __restrict__ W_hh, const float* __restrict__ b_ih,
    const float* __restrict__ b_hh, const float* __restrict__ W_fc,
    const float* __restrict__ b_fc, float* __restrict__ out)
{
    const int b   = blockIdx.x;
    const int tid = threadIdx.x;        // 0..255
    const int l   = tid & 63;
    const int wv  = tid >> 6;           // 0..3
    const int kb  = wv << 5;            // this wave's k-quarter base
    const int rA  = l;                  // partial rows this lane computes
    const int rB  = l + 64;
    const int rF  = (wv << 5) + (l & 31);   // row this wave finalizes

    __shared__ float xs[TT];            // input sequence
    __shared__ f32x2 p2[2][4][64];      // [buf][src wave][lane]={pA,pB}
    __shared__ f32x2 qp[2][4];          // [buf][wave] logit partials

    // preload x row (256 lanes x f32x4 = 1024 floats, coalesced)
    {
        const f32x4* xr = (const f32x4*)(x + (size_t)b * TT);
        ((f32x4*)xs)[tid] = xr[tid];
    }

    // finalized-row constants
    const float wih  = W_ih[rF];
    const float bias = b_ih[rF] + b_hh[rF];
    const float wf0  = W_fc[rF];
    const float wf1  = W_fc[HH + rF];
    const float bf0  = b_fc[0], bf1 = b_fc[1];

    // packed weights: wp[k] = { W_hh[rA][kb+k], W_hh[rB][kb+k] }, k<32
    // 32 f32x2 = 64 VGPRs (half of R5's budget -> expect resident)
    f32x2 wp[32];
    {
        const f32x4* a4 = (const f32x4*)(W_hh + (size_t)rA * HH + kb);
        const f32x4* b4 = (const f32x4*)(W_hh + (size_t)rB * HH + kb);
        #pragma unroll
        for (int j = 0; j < 8; ++j) {
            f32x4 va = a4[j], vb = b4[j];
            wp[4*j+0] = f32x2{va.x, vb.x};
            wp[4*j+1] = f32x2{va.y, vb.y};
            wp[4*j+2] = f32x2{va.z, vb.z};
            wp[4*j+3] = f32x2{va.w, vb.w};
        }
    }

    // combine-phase addressing (uniform per lane)
    const int qsel = (l >> 5) << 1;     // lanes 0..31 read quarters 0,1; 32..63: 2,3
    const int li   = rF & 63;           // lane index within p2's lane dim
    const int comp = rF >> 6;           // 0 -> .x (rows<64), 1 -> .y

    float hn = 0.f;                     // h[rF] (valid in lanes 0..31; dup in 32..63)
    float* o = out + (size_t)b * TT * CC;

    __syncthreads();                    // xs visible

    #pragma unroll 2
    for (int t = 0; t < TT; ++t) {
        const int buf = t & 1;

        // ---- partial matvec over this wave's k-quarter; h via readlane (VALU)
        f32x2 a0 = {0.f,0.f}, a1 = {0.f,0.f}, a2 = {0.f,0.f}, a3 = {0.f,0.f};
        #pragma unroll
        for (int k = 0; k < 32; k += 4) {
            float s0 = bcast(hn, k+0);
            float s1 = bcast(hn, k+1);
            float s2 = bcast(hn, k+2);
            float s3 = bcast(hn, k+3);
            a0 = __builtin_elementwise_fma(wp[k+0], f32x2{s0,s0}, a0);
            a1 = __builtin_elementwise_fma(wp[k+1], f32x2{s1,s1}, a1);
            a2 = __builtin_elementwise_fma(wp[k+2], f32x2{s2,s2}, a2);
            a3 = __builtin_elementwise_fma(wp[k+3], f32x2{s3,s3}, a3);
        }
        f32x2 pr = (a0 + a1) + (a2 + a3);
        p2[buf][wv][l] = pr;            // single b64 write

        __syncthreads();                // the per-step barrier

        // out[t-1] = logits(h_t) — qp written pre-barrier last iteration
        if (t > 0 && tid == 0) {
            const int pb = buf ^ 1;
            f32x2 s = (qp[pb][0] + qp[pb][1]) + (qp[pb][2] + qp[pb][3]);
            s.x += bf0; s.y += bf1;
            *(f32x2*)(o + (t - 1) * CC) = s;
        }

        // ---- combine 4 partials of row rF (2 via LDS, 1 via shfl_xor 32)
        float c0 = ((const float*)&p2[buf][qsel    ][li])[comp];
        float c1 = ((const float*)&p2[buf][qsel + 1][li])[comp];
        float sum = c0 + c1;
        sum += __shfl_xor(sum, 32);
        float u = fmaf(xs[t], wih, bias) + sum;
        hn = ftanh(u);

        // ---- logit partials over this wave's 32 rows (lanes 0..31 only)
        float q0 = (l < 32) ? wf0 * hn : 0.f;
        float q1 = (l < 32) ? wf1 * hn : 0.f;
        q0 += __shfl_xor(q0, 1);  q1 += __shfl_xor(q1, 1);
        q0 += __shfl_xor(q0, 2);  q1 += __shfl_xor(q1, 2);
        q0 += __shfl_xor(q0, 4);  q1 += __shfl_xor(q1, 4);
        q0 += __shfl_xor(q0, 8);  q1 += __shfl_xor(q1, 8);
        q0 += __shfl_xor(q0, 16); q1 += __shfl_xor(q1, 16);
        if (l == 0) qp[buf][wv] = f32x2{q0, q1};
    }

    // epilogue: out[TT-1] = logits(h_TT)
    __syncthreads();
    if (tid == 0) {
        const int pb = (TT - 1) & 1;
        f32x2 s = (qp[pb][0] + qp[pb][1]) + (qp[pb][2] + qp[pb][3]);
        s.x += bf0; s.y += bf1;
        *(f32x2*)(o + (TT - 1) * CC) = s;
    }
}

extern "C" void kernel_launch(void* const* d_in, const int* in_sizes, int n_in,
                              void* d_out, int out_size, void* d_ws, size_t ws_size,
                              hipStream_t stream) {
    const float* x    = (const float*)d_in[0];
    const float* W_ih = (const float*)d_in[1];
    const float* W_hh = (const float*)d_in[2];
    const float* b_ih = (const float*)d_in[3];
    const float* b_hh = (const float*)d_in[4];
    const float* W_fc = (const float*)d_in[5];
    const float* b_fc = (const float*)d_in[6];
    float* out = (float*)d_out;

    rnn_kernel<<<BB, 256, 0, stream>>>(x, W_ih, W_hh, b_ih, b_hh, W_fc, b_fc, out);
}